// Round 8
// baseline (271.616 us; speedup 1.0000x reference)
//
#include <hip/hip_runtime.h>
#include <hip/hip_bf16.h>
#include <hip/hip_fp16.h>

#define NN 50000
#define INCH 512
#define OUTCH 64
#define NTILES 3125       // 50000 / 16 (exact)
#define MAXD 96           // ELL slots per row; Poisson(16) tail ~1e-30
#define GB 782            // gemm blocks: ceil(3125 tiles / 4 waves)
#define SB 256            // scatter blocks appended after gemm blocks

typedef __attribute__((ext_vector_type(8))) short short8;
typedef __attribute__((ext_vector_type(4))) float floatx4;

__device__ __forceinline__ unsigned packbf2(float a, float b) {
    __hip_bfloat162 h = __float22bfloat162_rn(make_float2(a, b));  // v_cvt_pk_bf16_f32 RNE
    unsigned r;
    __builtin_memcpy(&r, &h, 4);
    return r;
}
__device__ __forceinline__ unsigned short f2bf(float f) {
    unsigned u = __float_as_uint(f);
    return (unsigned short)((u + 0x7FFFu + ((u >> 16) & 1u)) >> 16);  // RNE
}
__device__ __forceinline__ float bf2f(unsigned short u) {
    return __uint_as_float(((unsigned)u) << 16);
}

// ---------------- prep: zero deg + convert W fp32 [k][n] -> bf16 [n][k] global ----------
__global__ __launch_bounds__(256) void prep_kernel(const float* __restrict__ W,
                                                   unsigned short* __restrict__ Wbf,
                                                   int* __restrict__ deg) {
    const int i = blockIdx.x * 256 + threadIdx.x;
    if (i < NN) deg[i] = 0;
    if (i < INCH * OUTCH) {
        const int k = i >> 6;          // W is [k][n], read coalesced
        const int n = i & 63;
        Wbf[n * INCH + k] = f2bf(W[i]);
    }
}

// ---------------- fused: [blocks 0..GB) gemm | [GB..GB+SB) ELL scatter ----------------
// gemm: whole bf16 W staged once into 64-KB LDS with granule XOR-swizzle
// (pg = g ^ (n&7)) -> conflict-free ds_read_b128 in the K-loop.
// A-loads half-hoisted (16 dwordx4 in flight) -> HBM-streaming.
// Epilogue: per-wave LDS transpose -> coalesced 1-KB bf16 stores.
__global__ __launch_bounds__(256) void fused_gemm_scatter(
        const float* __restrict__ A, const unsigned short* __restrict__ Wbf,
        unsigned short* __restrict__ C,
        const int* __restrict__ rows, const int* __restrict__ cols,
        const float* __restrict__ vals, int* __restrict__ deg,
        unsigned* __restrict__ ell, int E_) {
    __shared__ unsigned short Ws[64 * 512];       // 64 KB, swizzled
    __shared__ unsigned short ldsT[4][16 * 64];   // 8 KB transpose buffer
    const int t = threadIdx.x;

    if (blockIdx.x >= GB) {
        // ---------- scatter part (never touches the barriers) ----------
        for (int e = (blockIdx.x - GB) * 256 + t; e < E_; e += SB * 256) {
            const int r = rows[e];
            const int slot = atomicAdd(&deg[r], 1);
            const unsigned short hv = __half_as_ushort(__float2half(vals[e]));
            if (slot < MAXD)
                ell[(size_t)r * MAXD + slot] = (unsigned)cols[e] | ((unsigned)hv << 16);
        }
        return;
    }

    // ---------- stage W into swizzled LDS ----------
    {
        const int n = t & 63;           // lane = row -> write banks fully spread
        const int gset = t >> 6;        // 4 granule-sets of 16
#pragma unroll
        for (int i = 0; i < 16; ++i) {
            const int g = gset * 16 + i;                 // logical granule (8 shorts)
            const short8 v = *(const short8*)(Wbf + n * INCH + g * 8);
            const int pg = g ^ (n & 7);                  // XOR swizzle
            *(short8*)&Ws[n * 512 + pg * 8] = v;
        }
    }
    __syncthreads();

    // ---------- gemm ----------
    const int lane = t & 63;
    const int wave = t >> 6;
    const int tileRaw = blockIdx.x * 4 + wave;
    const int tile = (tileRaw < NTILES) ? tileRaw : (NTILES - 1);  // clamp, no early return
    const bool active = (tileRaw < NTILES);
    const int rbase = tile * 16;
    const int frow = lane & 15;
    const int quad = lane >> 4;
    const float* Ap = A + (size_t)(rbase + frow) * INCH + quad * 8;
    const int fsw = frow & 7;

    floatx4 acc[4] = {floatx4{0,0,0,0}, floatx4{0,0,0,0}, floatx4{0,0,0,0}, floatx4{0,0,0,0}};

    float4 abuf[16];
    for (int h = 0; h < 2; ++h) {
        // issue 16 independent dwordx4 loads (8 K-chunks) before consuming
#pragma unroll
        for (int c = 0; c < 8; ++c) {
            abuf[c * 2 + 0] = *(const float4*)(Ap + (h * 8 + c) * 32);
            abuf[c * 2 + 1] = *(const float4*)(Ap + (h * 8 + c) * 32 + 4);
        }
#pragma unroll
        for (int c = 0; c < 8; ++c) {
            const int cc = h * 8 + c;
            const float4 a0 = abuf[c * 2 + 0];
            const float4 a1 = abuf[c * 2 + 1];
            uint4 au;
            au.x = packbf2(a0.x, a0.y);
            au.y = packbf2(a0.z, a0.w);
            au.z = packbf2(a1.x, a1.y);
            au.w = packbf2(a1.z, a1.w);
            const short8 af = *(const short8*)&au;
            const int pg = (cc * 4 + quad) ^ fsw;        // swizzled granule
#pragma unroll
            for (int f = 0; f < 4; ++f) {
                const short8 bfr = *(const short8*)&Ws[(f * 16 + frow) * 512 + pg * 8];
                acc[f] = __builtin_amdgcn_mfma_f32_16x16x32_bf16(af, bfr, acc[f], 0, 0, 0);
            }
        }
    }

    // ---------- epilogue: wave-local LDS transpose, coalesced stores ----------
    // C/D layout: col = f*16 + frow, row = quad*4 + reg   [m89]
    if (active) {
        unsigned short* myT = ldsT[wave];
#pragma unroll
        for (int f = 0; f < 4; ++f)
#pragma unroll
            for (int reg = 0; reg < 4; ++reg)
                myT[(quad * 4 + reg) * 64 + f * 16 + frow] = f2bf(acc[f][reg]);
        unsigned short* Cw = C + (size_t)rbase * OUTCH;
#pragma unroll
        for (int it = 0; it < 2; ++it) {
            const short8 v = *(const short8*)&myT[it * 512 + lane * 8];
            *(short8*)(Cw + it * 512 + lane * 8) = v;
        }
    }
}

// ---------------- SpMM over ELL: one wave per row, 4 edge-slots x 16 lanes ----------
// xin is bf16 [N,64]; LAST=false -> write bf16, LAST=true -> +bias, write fp32.
template <bool LAST>
__global__ __launch_bounds__(256) void spmm_ell(const int* __restrict__ deg,
                                                const unsigned* __restrict__ ell,
                                                const unsigned short* __restrict__ xin,
                                                void* __restrict__ xout_,
                                                const float* __restrict__ bias) {
    const int t = threadIdx.x;
    const int lane = t & 63;
    const int eslot = lane >> 4;        // 0..3: edge slot
    const int c4 = (lane & 15) * 4;     // channel base
    const int row = blockIdx.x * 4 + (t >> 6);   // NN = 4 * 12500 exact
    const int d = deg[row];
    const unsigned* ebase = ell + (size_t)row * MAXD;
    float4 acc = make_float4(0.f, 0.f, 0.f, 0.f);
    int i = eslot;
    unsigned p = (i < d) ? ebase[i] : 0u;
    while (i < d) {
        const int inext = i + 4;
        const unsigned pn = (inext < d) ? ebase[inext] : 0u;   // prefetch next edge
        const ushort4 xv = *(const ushort4*)(xin + (size_t)(p & 0xFFFFu) * OUTCH + c4);
        const float v = __half2float(__ushort_as_half((unsigned short)(p >> 16)));
        acc.x = fmaf(v, bf2f(xv.x), acc.x);
        acc.y = fmaf(v, bf2f(xv.y), acc.y);
        acc.z = fmaf(v, bf2f(xv.z), acc.z);
        acc.w = fmaf(v, bf2f(xv.w), acc.w);
        p = pn;
        i = inext;
    }
    // reduce the 4 edge-slots (lane bits 4,5)
    acc.x += __shfl_xor(acc.x, 16, 64); acc.y += __shfl_xor(acc.y, 16, 64);
    acc.z += __shfl_xor(acc.z, 16, 64); acc.w += __shfl_xor(acc.w, 16, 64);
    acc.x += __shfl_xor(acc.x, 32, 64); acc.y += __shfl_xor(acc.y, 32, 64);
    acc.z += __shfl_xor(acc.z, 32, 64); acc.w += __shfl_xor(acc.w, 32, 64);
    if (eslot == 0) {
        if (LAST) {
            const float4 bv = *(const float4*)(bias + c4);
            acc.x += bv.x; acc.y += bv.y; acc.z += bv.z; acc.w += bv.w;
            *(float4*)((float*)xout_ + (size_t)row * OUTCH + c4) = acc;
        } else {
            ushort4 o;
            o.x = f2bf(acc.x); o.y = f2bf(acc.y); o.z = f2bf(acc.z); o.w = f2bf(acc.w);
            *(ushort4*)((unsigned short*)xout_ + (size_t)row * OUTCH + c4) = o;
        }
    }
}

extern "C" void kernel_launch(void* const* d_in, const int* in_sizes, int n_in,
                              void* d_out, int out_size, void* d_ws, size_t ws_size,
                              hipStream_t stream) {
    const int*   adj   = (const int*)d_in[0];     // [2, E]
    const float* avals = (const float*)d_in[1];   // [E]
    const float* feat  = (const float*)d_in[2];   // [N, 512]
    const float* W     = (const float*)d_in[3];   // [512, 64]
    const float* bias  = (const float*)d_in[4];   // [64]
    float* out = (float*)d_out;

    const int E_ = in_sizes[1];
    const int* rows = adj;
    const int* cols = adj + E_;

    // workspace layout (16B-aligned segments)
    unsigned short* x0  = (unsigned short*)d_ws;            // N*64 bf16 (6.4 MB)
    unsigned short* x1  = x0 + (size_t)NN * OUTCH;          // N*64 bf16 (6.4 MB)
    unsigned short* Wbf = x1 + (size_t)NN * OUTCH;          // 64*512 bf16 (64 KB)
    unsigned* ell = (unsigned*)(Wbf + (size_t)OUTCH * INCH);// N*MAXD u32 (19.2 MB)
    int* deg = (int*)(ell + (size_t)NN * MAXD);             // N

    // ---- prep: zero deg + convert W to bf16 [n][k] ----
    prep_kernel<<<(NN + 255) / 256, 256, 0, stream>>>(W, Wbf, deg);

    // ---- fused: dense projection (bf16 MFMA) + ELL scatter ----
    fused_gemm_scatter<<<GB + SB, 256, 0, stream>>>(feat, Wbf, x0, rows, cols, avals,
                                                    deg, ell, E_);

    // ---- two SpMM hops; bias fused into the last ----
    spmm_ell<false><<<NN / 4, 256, 0, stream>>>(deg, ell, x0, x1, nullptr);
    spmm_ell<true><<<NN / 4, 256, 0, stream>>>(deg, ell, x1, out, bias);
}

// Round 9
// 262.442 us; speedup vs baseline: 1.0350x; 1.0350x over previous
//
#include <hip/hip_runtime.h>
#include <hip/hip_bf16.h>
#include <hip/hip_fp16.h>

#define NN 50000
#define INCH 512
#define OUTCH 64
#define MAXD 96           // ELL slots per row; Poisson(16) tail ~1e-30
#define SB 256            // scatter blocks (run FIRST for overlap)
#define NT32 1563         // ceil(50000/32) 32-row wave-tiles
#define GB2 391           // ceil(NT32/4) gemm blocks

typedef __attribute__((ext_vector_type(8))) short short8;
typedef __attribute__((ext_vector_type(4))) float floatx4;

__device__ __forceinline__ unsigned packbf2(float a, float b) {
    __hip_bfloat162 h = __float22bfloat162_rn(make_float2(a, b));  // v_cvt_pk_bf16_f32 RNE
    unsigned r;
    __builtin_memcpy(&r, &h, 4);
    return r;
}
__device__ __forceinline__ unsigned short f2bf(float f) {
    unsigned u = __float_as_uint(f);
    return (unsigned short)((u + 0x7FFFu + ((u >> 16) & 1u)) >> 16);  // RNE
}
__device__ __forceinline__ float bf2f(unsigned short u) {
    return __uint_as_float(((unsigned)u) << 16);
}

// ---------------- prep: zero deg + convert W fp32 [k][n] -> bf16 [n][k] global ----------
__global__ __launch_bounds__(256) void prep_kernel(const float* __restrict__ W,
                                                   unsigned short* __restrict__ Wbf,
                                                   int* __restrict__ deg) {
    const int i = blockIdx.x * 256 + threadIdx.x;
    if (i < NN) deg[i] = 0;
    if (i < INCH * OUTCH) {
        const int k = i >> 6;          // W is [k][n], read coalesced
        const int n = i & 63;
        Wbf[n * INCH + k] = f2bf(W[i]);
    }
}

// ---------------- fused: [blocks 0..SB) ELL scatter | [SB..SB+GB2) gemm ----------------
// gemm: no W-LDS (B-frags from L2-resident global Wbf); 32 rows per wave (2 sub-tiles
// share each chunk's 4 B-fragments -> half the B L1-transaction flood per row);
// A-loads non-temporal (keep L2 for ELL/B). Epilogue: per-wave LDS transpose ->
// coalesced 1-KB bf16 stores.
__global__ __launch_bounds__(256, 4) void fused_gemm_scatter(
        const float* __restrict__ A, const unsigned short* __restrict__ Wbf,
        unsigned short* __restrict__ C,
        const int* __restrict__ rows, const int* __restrict__ cols,
        const float* __restrict__ vals, int* __restrict__ deg,
        unsigned* __restrict__ ell, int E_) {
    __shared__ unsigned short ldsT[4][16 * 64];   // 8 KB transpose buffer
    const int t = threadIdx.x;

    if (blockIdx.x < SB) {
        // ---------- scatter part (first in dispatch order -> overlaps gemm) ----------
        for (int e = blockIdx.x * 256 + t; e < E_; e += SB * 256) {
            const int r = rows[e];
            const int slot = atomicAdd(&deg[r], 1);
            const unsigned short hv = __half_as_ushort(__float2half(vals[e]));
            if (slot < MAXD)
                ell[(size_t)r * MAXD + slot] = (unsigned)cols[e] | ((unsigned)hv << 16);
        }
        return;
    }

    // ---------- gemm part ----------
    const int lane = t & 63;
    const int wave = t >> 6;
    const int tileRaw = (blockIdx.x - SB) * 4 + wave;
    const int tile = (tileRaw < NT32) ? tileRaw : (NT32 - 1);
    const int rbase = tile * 32;
    const int frow = lane & 15;
    const int quad = lane >> 4;

    int r0 = rbase + frow;       if (r0 > NN - 1) r0 = NN - 1;   // clamp loads
    int r1 = rbase + 16 + frow;  if (r1 > NN - 1) r1 = NN - 1;
    const float* Ap0 = A + (size_t)r0 * INCH + quad * 8;
    const float* Ap1 = A + (size_t)r1 * INCH + quad * 8;
    const unsigned short* Bp = Wbf + frow * INCH + quad * 8;

    floatx4 acc0[4] = {floatx4{0,0,0,0}, floatx4{0,0,0,0}, floatx4{0,0,0,0}, floatx4{0,0,0,0}};
    floatx4 acc1[4] = {floatx4{0,0,0,0}, floatx4{0,0,0,0}, floatx4{0,0,0,0}, floatx4{0,0,0,0}};

#pragma unroll
    for (int c = 0; c < 16; ++c) {
        const floatx4 a00 = __builtin_nontemporal_load((const floatx4*)(Ap0 + c * 32));
        const floatx4 a01 = __builtin_nontemporal_load((const floatx4*)(Ap0 + c * 32 + 4));
        const floatx4 a10 = __builtin_nontemporal_load((const floatx4*)(Ap1 + c * 32));
        const floatx4 a11 = __builtin_nontemporal_load((const floatx4*)(Ap1 + c * 32 + 4));
        short8 bfr[4];
#pragma unroll
        for (int f = 0; f < 4; ++f)
            bfr[f] = *(const short8*)(Bp + (size_t)f * 16 * INCH + c * 32);
        uint4 u0, u1;
        u0.x = packbf2(a00[0], a00[1]); u0.y = packbf2(a00[2], a00[3]);
        u0.z = packbf2(a01[0], a01[1]); u0.w = packbf2(a01[2], a01[3]);
        u1.x = packbf2(a10[0], a10[1]); u1.y = packbf2(a10[2], a10[3]);
        u1.z = packbf2(a11[0], a11[1]); u1.w = packbf2(a11[2], a11[3]);
        const short8 af0 = *(const short8*)&u0;
        const short8 af1 = *(const short8*)&u1;
#pragma unroll
        for (int f = 0; f < 4; ++f) {
            acc0[f] = __builtin_amdgcn_mfma_f32_16x16x32_bf16(af0, bfr[f], acc0[f], 0, 0, 0);
            acc1[f] = __builtin_amdgcn_mfma_f32_16x16x32_bf16(af1, bfr[f], acc1[f], 0, 0, 0);
        }
    }

    // ---------- epilogue: wave-local LDS transpose, coalesced predicated stores ----------
    // C/D layout: col = f*16 + frow, row = quad*4 + reg   [m89]
    unsigned short* myT = ldsT[wave];
#pragma unroll
    for (int s = 0; s < 2; ++s) {
        const floatx4* acc = s ? acc1 : acc0;
#pragma unroll
        for (int f = 0; f < 4; ++f)
#pragma unroll
            for (int reg = 0; reg < 4; ++reg)
                myT[(quad * 4 + reg) * 64 + f * 16 + frow] = f2bf(acc[f][reg]);
        // wave-local DS ops execute in order; no barrier needed
        unsigned short* Cw = C + (size_t)(rbase + s * 16) * OUTCH;
#pragma unroll
        for (int it = 0; it < 2; ++it) {
            const int rowg = rbase + s * 16 + it * 8 + (lane >> 3);
            const short8 v = *(const short8*)&myT[it * 512 + lane * 8];
            if (rowg < NN)
                *(short8*)(Cw + it * 512 + lane * 8) = v;
        }
    }
}

// ---------------- SpMM over ELL: one wave per row, 4 edge-slots x 16 lanes ----------
// xin is bf16 [N,64]; LAST=false -> write bf16, LAST=true -> +bias, write fp32.
template <bool LAST>
__global__ __launch_bounds__(256) void spmm_ell(const int* __restrict__ deg,
                                                const unsigned* __restrict__ ell,
                                                const unsigned short* __restrict__ xin,
                                                void* __restrict__ xout_,
                                                const float* __restrict__ bias) {
    const int t = threadIdx.x;
    const int lane = t & 63;
    const int eslot = lane >> 4;        // 0..3: edge slot
    const int c4 = (lane & 15) * 4;     // channel base
    const int row = blockIdx.x * 4 + (t >> 6);   // NN = 4 * 12500 exact
    const int d = deg[row];
    const unsigned* ebase = ell + (size_t)row * MAXD;
    float4 acc = make_float4(0.f, 0.f, 0.f, 0.f);
    int i = eslot;
    unsigned p = (i < d) ? ebase[i] : 0u;
    while (i < d) {
        const int inext = i + 4;
        const unsigned pn = (inext < d) ? ebase[inext] : 0u;   // prefetch next edge
        const ushort4 xv = *(const ushort4*)(xin + (size_t)(p & 0xFFFFu) * OUTCH + c4);
        const float v = __half2float(__ushort_as_half((unsigned short)(p >> 16)));
        acc.x = fmaf(v, bf2f(xv.x), acc.x);
        acc.y = fmaf(v, bf2f(xv.y), acc.y);
        acc.z = fmaf(v, bf2f(xv.z), acc.z);
        acc.w = fmaf(v, bf2f(xv.w), acc.w);
        p = pn;
        i = inext;
    }
    // reduce the 4 edge-slots (lane bits 4,5)
    acc.x += __shfl_xor(acc.x, 16, 64); acc.y += __shfl_xor(acc.y, 16, 64);
    acc.z += __shfl_xor(acc.z, 16, 64); acc.w += __shfl_xor(acc.w, 16, 64);
    acc.x += __shfl_xor(acc.x, 32, 64); acc.y += __shfl_xor(acc.y, 32, 64);
    acc.z += __shfl_xor(acc.z, 32, 64); acc.w += __shfl_xor(acc.w, 32, 64);
    if (eslot == 0) {
        if (LAST) {
            const float4 bv = *(const float4*)(bias + c4);
            acc.x += bv.x; acc.y += bv.y; acc.z += bv.z; acc.w += bv.w;
            *(float4*)((float*)xout_ + (size_t)row * OUTCH + c4) = acc;
        } else {
            ushort4 o;
            o.x = f2bf(acc.x); o.y = f2bf(acc.y); o.z = f2bf(acc.z); o.w = f2bf(acc.w);
            *(ushort4*)((unsigned short*)xout_ + (size_t)row * OUTCH + c4) = o;
        }
    }
}

extern "C" void kernel_launch(void* const* d_in, const int* in_sizes, int n_in,
                              void* d_out, int out_size, void* d_ws, size_t ws_size,
                              hipStream_t stream) {
    const int*   adj   = (const int*)d_in[0];     // [2, E]
    const float* avals = (const float*)d_in[1];   // [E]
    const float* feat  = (const float*)d_in[2];   // [N, 512]
    const float* W     = (const float*)d_in[3];   // [512, 64]
    const float* bias  = (const float*)d_in[4];   // [64]
    float* out = (float*)d_out;

    const int E_ = in_sizes[1];
    const int* rows = adj;
    const int* cols = adj + E_;

    // workspace layout (16B-aligned segments)
    unsigned short* x0  = (unsigned short*)d_ws;            // N*64 bf16 (6.4 MB)
    unsigned short* x1  = x0 + (size_t)NN * OUTCH;          // N*64 bf16 (6.4 MB)
    unsigned short* Wbf = x1 + (size_t)NN * OUTCH;          // 64*512 bf16 (64 KB)
    unsigned* ell = (unsigned*)(Wbf + (size_t)OUTCH * INCH);// N*MAXD u32 (19.2 MB)
    int* deg = (int*)(ell + (size_t)NN * MAXD);             // N

    // ---- prep: zero deg + convert W to bf16 [n][k] ----
    prep_kernel<<<(NN + 255) / 256, 256, 0, stream>>>(W, Wbf, deg);

    // ---- fused: ELL scatter (first) + dense projection (bf16 MFMA) ----
    fused_gemm_scatter<<<SB + GB2, 256, 0, stream>>>(feat, Wbf, x0, rows, cols, avals,
                                                     deg, ell, E_);

    // ---- two SpMM hops; bias fused into the last ----
    spmm_ell<false><<<NN / 4, 256, 0, stream>>>(deg, ell, x0, x1, nullptr);
    spmm_ell<true><<<NN / 4, 256, 0, stream>>>(deg, ell, x1, out, bias);
}